// Round 1
// 516.761 us; speedup vs baseline: 1.7183x; 1.7183x over previous
//
#include <hip/hip_runtime.h>
#include <hip/hip_bf16.h>
#include <stdint.h>

typedef __hip_bfloat16 bf16;
typedef unsigned long long u64;
typedef unsigned int u32;
typedef short short8 __attribute__((ext_vector_type(8)));
typedef float f32x4 __attribute__((ext_vector_type(4)));

#define D_ 128   // memory dim
#define K_ 640   // X' width: [mem_n | mem_other | time_enc | feat | h]
// fallback tile (proven kernel)
#define BM 64
#define BN 128
#define BK 64
// new tile
#define BM2 32

__device__ __forceinline__ float bf2f(bf16 v) { return __bfloat162float(v); }
__device__ __forceinline__ u32 fbits(float f) { union { float f; u32 u; } c; c.f = f; return c.u; }
__device__ __forceinline__ u32 pk2(float a, float b) {
  union { bf16 h; unsigned short s; } x, y;
  x.h = __float2bfloat16(a); y.h = __float2bfloat16(b);
  return (u32)x.s | ((u32)y.s << 16);
}
template<bool F32>
__device__ __forceinline__ float ldE(const void* p, size_t i) {
  return F32 ? ((const float*)p)[i] : bf2f(((const bf16*)p)[i]);
}
template<bool F32>
__device__ __forceinline__ void stE(void* p, size_t i, float v) {
  if (F32) ((float*)p)[i] = v; else ((bf16*)p)[i] = __float2bfloat16(v);
}
// load 8 source elements (bf16 or fp32) as 8 bf16 packed in a uint4
template<bool F32>
__device__ __forceinline__ uint4 ld8(const void* base, size_t elemOff) {
  if (!F32) {
    return *(const uint4*)((const bf16*)base + elemOff);
  } else {
    const float4* p = (const float4*)((const float*)base + elemOff);
    float4 v0 = p[0], v1 = p[1];
    uint4 o; o.x = pk2(v0.x, v0.y); o.y = pk2(v0.z, v0.w);
    o.z = pk2(v1.x, v1.y); o.w = pk2(v1.z, v1.w);
    return o;
  }
}
template<bool F32>
__device__ __forceinline__ void stage8(const void* base, size_t elemOff, bf16* dst) {
  *(uint4*)dst = ld8<F32>(base, elemOff);
}
// async global->LDS, 16B per lane; lds ptr must be wave-uniform
__device__ __forceinline__ void gl_lds16(const void* g, void* l) {
  __builtin_amdgcn_global_load_lds(
      (const __attribute__((address_space(1))) unsigned int*)g,
      (__attribute__((address_space(3))) unsigned int*)l, 16, 0, 0);
}

// ---- prep: zero scatter keys + cnt, sniff dtype (0 = bf16, 1 = fp32) ------
__global__ void k_prep(u64* __restrict__ key, u32* __restrict__ cnt, int N,
                       const u32* __restrict__ mem_w, const u32* __restrict__ t_w,
                       u32* __restrict__ flag) {
  int i = blockIdx.x * blockDim.x + threadIdx.x;
  if (i < N) key[i] = 0ull;
  if (i == 0) {
    *cnt = 0u;
    int ok = 1;
    for (int k = 0; k < 64; ++k) {
      u32 w = mem_w[k];
      if ((w & 0x7fffu) > 0x4300u) ok = 0;
      if (((w >> 16) & 0x7fffu) > 0x4300u) ok = 0;
    }
    for (int k = 0; k < 16; ++k) {
      u32 w = t_w[k];
      if ((w & 0xffffu) > 0x4480u) ok = 0;
      if ((w >> 16) > 0x4480u) ok = 0;
    }
    *flag = ok ? 0u : 1u;
  }
}

// ---- single scatter pass: per-node lexicographic max of (t_bits, pos+1) ---
// Matches ref tie-break: among max-t events take max original index.
__global__ void k_scat(const int* __restrict__ src, const int* __restrict__ dst,
                       const void* __restrict__ t, const u32* __restrict__ flag,
                       u64* __restrict__ key, int E) {
  int i = blockIdx.x * blockDim.x + threadIdx.x;
  if (i >= 2 * E) return;
  int e = (i < E) ? i : i - E;
  int node = (i < E) ? src[e] : dst[e];
  float tv = (*flag) ? ((const float*)t)[e] : bf2f(((const bf16*)t)[e]);
  u64 k = ((u64)fbits(tv) << 32) | (u64)(u32)(i + 1);  // t >= 0: bit order == value order
  atomicMax(&key[node], k);
}

// ---- pack weights: bf16, tile-ordered [tile=kc*4+by][128 j][64 k], XOR-swizzled
// within tile: byte = (j*128 + 16*s) ^ ((j&7)<<4)  (s = 16B group index)
__global__ void k_pack(const void* __restrict__ wih, const void* __restrict__ whh,
                       const u32* __restrict__ flag, bf16* __restrict__ wpk) {
  int gid = blockIdx.x * 256 + threadIdx.x;
  if (gid >= 40960) return;                // 40 tiles x 1024 16B-groups
  int tile = gid >> 10, r = gid & 1023;
  int j = r >> 3, s = r & 7;
  int kc = tile >> 2, by = tile & 3;
  int kglob = kc * 64 + s * 8;
  int grp = j >> 5, gi = j & 31, gidx = 32 * by + gi;
  int srow = (grp == 0) ? gidx : (grp == 1) ? 128 + gidx : 256 + gidx;
  bool zero = (kglob < 512) ? (grp == 3) : (grp == 2);
  uint4 v;
  if (zero) v = (uint4){0u, 0u, 0u, 0u};
  else if (*flag) v = (kglob < 512) ? ld8<true>(wih, (size_t)srow * 512 + kglob)
                                    : ld8<true>(whh, (size_t)srow * 128 + (kglob - 512));
  else            v = (kglob < 512) ? ld8<false>(wih, (size_t)srow * 512 + kglob)
                                    : ld8<false>(whh, (size_t)srow * 128 + (kglob - 512));
  ((uint4*)wpk)[(size_t)tile * 1024 + ((j * 8 + s) ^ (j & 7))] = v;
}

// ---- compact: passthrough inactive rows, out_last for all, optional list ---
template<bool F32>
__device__ __forceinline__ void compact_body(int n, const void* mem, const void* lastup,
                                             const void* t, const u64* key,
                                             int* list, u32* cnt, int use_list,
                                             void* out, int N, int E) {
  u32 b = (u32)key[n];
  if (b) {
    int pos = (int)(b - 1u);
    int e = (pos < E) ? pos : pos - E;
    stE<F32>(out, (size_t)N * D_ + n, ldE<F32>(t, e));
    if (use_list) { u32 idx = atomicAdd(cnt, 1u); list[idx] = n; }
  } else {
    if (F32) {
      const float4* s = (const float4*)((const float*)mem + (size_t)n * D_);
      float4* d = (float4*)((float*)out + (size_t)n * D_);
#pragma unroll
      for (int i = 0; i < 32; ++i) d[i] = s[i];
    } else {
      const uint4* s = (const uint4*)((const bf16*)mem + (size_t)n * D_);
      uint4* d = (uint4*)((bf16*)out + (size_t)n * D_);
#pragma unroll
      for (int i = 0; i < 16; ++i) d[i] = s[i];
    }
    stE<F32>(out, (size_t)N * D_ + n, ldE<F32>(lastup, n));
  }
}
__global__ void k_compact(const void* mem, const void* lastup, const void* t,
                          const u32* __restrict__ flag, const u64* __restrict__ key,
                          int* list, u32* cnt, int use_list,
                          void* out, int N, int E) {
  int n = blockIdx.x * blockDim.x + threadIdx.x;
  if (n >= N) return;
  if (*flag) compact_body<true>(n, mem, lastup, t, key, list, cnt, use_list, out, N, E);
  else       compact_body<false>(n, mem, lastup, t, key, list, cnt, use_list, out, N, E);
}

// ============================================================================
// NEW fused GEMM+GRU: one block = 32 rows x ALL 512 gate-cols (by-loop inside).
// A gathered once (was 4x), cosf once (was 4x). B staged async from packed
// bf16 weights via global_load_lds, double-buffered one phase ahead.
// ============================================================================
template<bool F32>
__device__ __forceinline__ uint4 a_fetch(int kc, int tid,
    const void* mem, const void* feat,
    const int* s_node, const int* s_e, const int* s_oth,
    const float* s_dt, const float* s_tw, const float* s_tb) {
  int r = tid >> 3, s = tid & 7;
  int k0 = kc * 64 + s * 8;        // each kc maps to exactly one source region
  if (k0 < 128) return ld8<F32>(mem, (size_t)s_node[r] * D_ + k0);
  if (k0 < 256) return ld8<F32>(mem, (size_t)s_oth[r] * D_ + (k0 - 128));
  if (k0 < 384) {
    float dtv = s_dt[r];
    float f[8];
#pragma unroll
    for (int q = 0; q < 8; ++q) {
      int j = k0 - 256 + q;
      f[q] = cosf(fmaf(dtv, s_tw[j], s_tb[j]));
    }
    uint4 o; o.x = pk2(f[0], f[1]); o.y = pk2(f[2], f[3]);
    o.z = pk2(f[4], f[5]); o.w = pk2(f[6], f[7]);
    return o;
  }
  if (k0 < 512) return ld8<F32>(feat, (size_t)s_e[r] * D_ + (k0 - 384));
  return ld8<F32>(mem, (size_t)s_node[r] * D_ + (k0 - 512));
}

// stage one 128x64 bf16 B-tile (16KB) : 4 x global_load_lds(16B) per thread
__device__ __forceinline__ void b_issue(const bf16* __restrict__ wpk, int tile,
                                        bf16* BsBuf, int tid) {
  int w = tid >> 6;
  const bf16* g = wpk + (size_t)tile * 8192 + w * 2048 + (tid & 63) * 8;
  bf16* l = BsBuf + w * 2048;      // wave-uniform; HW adds lane*16B
#pragma unroll
  for (int i = 0; i < 4; ++i)
    gl_lds16(g + i * 512, l + i * 512);
}

template<bool F32>
__device__ __forceinline__ void gemm2_body(
    const void* mem, const void* lastup, const void* t, const void* feat,
    const int* __restrict__ src, const int* __restrict__ dst,
    const bf16* __restrict__ wpk,
    const void* bih, const void* bhh, const void* tw, const void* tb,
    const u64* __restrict__ key, const int* __restrict__ list,
    const u32* __restrict__ cnt, int use_list,
    void* out, int N, int E,
    char* smem, int* s_node, int* s_e, int* s_oth, int* s_act,
    float* s_dt, float* s_tw, float* s_tb) {
  const int tid = threadIdx.x;
  const int bx = blockIdx.x;
  bf16 (*As)[BM2][72] = (bf16 (*)[BM2][72])smem;         //  9216 B (2 bufs)
  bf16* BsBase = (bf16*)(smem + 9216);                    // 32768 B (2 bufs)
  float (*Gs)[133] = (float (*)[133])smem;                // overlay (epilogue)

  b_issue(wpk, 0, BsBase, tid);    // start weight tile 0 ASAP

  if (tid < BM2) {
    int r = tid, row = BM2 * bx + r, node = -1;
    if (use_list) { int c = (int)*cnt; if (row < c) node = list[row]; }
    else if (row < N) node = row;
    int act = 0, e = 0, oth = 0; float dtv = 0.f;
    if (node >= 0) {
      u32 b = (u32)key[node];
      if (b) {
        act = 1;
        int pos = (int)(b - 1u);
        if (pos < E) { e = pos; oth = dst[e]; } else { e = pos - E; oth = src[e]; }
        dtv = ldE<F32>(t, e) - ldE<F32>(lastup, node);
      }
    }
    if (node < 0) node = 0;
    s_node[r] = node; s_e[r] = e; s_oth[r] = oth; s_act[r] = act; s_dt[r] = dtv;
  }
  if (tid < 128) s_tw[tid] = ldE<F32>(tw, tid);
  else           s_tb[tid - 128] = ldE<F32>(tb, tid - 128);
  __syncthreads();

  {  // stage A(kc=0)
    uint4 a0 = a_fetch<F32>(0, tid, mem, feat, s_node, s_e, s_oth, s_dt, s_tw, s_tb);
    *(uint4*)&As[0][tid >> 3][(tid & 7) * 8] = a0;
  }
  __syncthreads();

  const int w = tid >> 6, l = tid & 63;
  const int mrow = l & 15, quad = l >> 4;
  f32x4 acc[4][2][2];   // [by][mi][ni] — all indices compile-time after unroll
#pragma unroll
  for (int by = 0; by < 4; ++by)
#pragma unroll
    for (int mi = 0; mi < 2; ++mi)
#pragma unroll
      for (int ni = 0; ni < 2; ++ni) acc[by][mi][ni] = (f32x4){0.f, 0.f, 0.f, 0.f};

  uint4 apre = (uint4){0u, 0u, 0u, 0u};
#pragma unroll 1
  for (int kc = 0; kc < K_ / 64; ++kc) {
    const int ka = kc & 1;
    short8 a[2][2];
#pragma unroll
    for (int by = 0; by < 4; ++by) {            // phase = kc*4+by; Bs buf = by&1
      const int tile = kc * 4 + by;
      if (by == 0) {
        if (kc + 1 < 10)
          apre = a_fetch<F32>(kc + 1, tid, mem, feat, s_node, s_e, s_oth, s_dt, s_tw, s_tb);
      }
      if (tile + 1 < 40)
        b_issue(wpk, tile + 1, BsBase + (((by & 1) ^ 1) << 13), tid);
      if (by == 0) {
#pragma unroll
        for (int ks2 = 0; ks2 < 2; ++ks2)
#pragma unroll
          for (int mi = 0; mi < 2; ++mi)
            a[ks2][mi] = *(const short8*)((const char*)&As[ka][0][0] +
                             (16 * mi + mrow) * 144 + ks2 * 64 + quad * 16);
      }
      const char* Bsb = (const char*)(BsBase + ((by & 1) << 13));
      short8 b[2][2];
#pragma unroll
      for (int ks2 = 0; ks2 < 2; ++ks2)
#pragma unroll
        for (int ni = 0; ni < 2; ++ni) {
          int j = 32 * w + 16 * ni + mrow;
          int off = (j * 128 + ks2 * 64 + quad * 16) ^ ((j & 7) << 4);
          b[ks2][ni] = *(const short8*)(Bsb + off);
        }
#pragma unroll
      for (int ks2 = 0; ks2 < 2; ++ks2)
#pragma unroll
        for (int mi = 0; mi < 2; ++mi)
#pragma unroll
          for (int ni = 0; ni < 2; ++ni)
            acc[by][mi][ni] = __builtin_amdgcn_mfma_f32_16x16x32_bf16(
                a[ks2][mi], b[ks2][ni], acc[by][mi][ni], 0, 0, 0);
      if (by == 3 && kc + 1 < 10)
        *(uint4*)&As[ka ^ 1][tid >> 3][(tid & 7) * 8] = apre;
      __syncthreads();   // drains vmcnt: next B tile + A prefetch landed
    }
  }

  // ---- GRU epilogue per by (Gs overlays the dead As/Bs region) ----
#pragma unroll
  for (int by = 0; by < 4; ++by) {
#pragma unroll
    for (int mi = 0; mi < 2; ++mi)
#pragma unroll
      for (int ni = 0; ni < 2; ++ni)
#pragma unroll
        for (int reg = 0; reg < 4; ++reg)
          Gs[16 * mi + quad * 4 + reg][32 * w + 16 * ni + mrow] = acc[by][mi][ni][reg];
    __syncthreads();
    {
      int r = tid >> 3, giB = (tid & 7) * 4;
      if (s_act[r]) {
        int node = s_node[r];
#pragma unroll
        for (int q = 0; q < 4; ++q) {
          int gi = giB + q, gidx = 32 * by + gi;
          float rp  = Gs[r][gi]      + ldE<F32>(bih, gidx)       + ldE<F32>(bhh, gidx);
          float zp  = Gs[r][32 + gi] + ldE<F32>(bih, 128 + gidx) + ldE<F32>(bhh, 128 + gidx);
          float inp = Gs[r][64 + gi] + ldE<F32>(bih, 256 + gidx);
          float hnp = Gs[r][96 + gi] + ldE<F32>(bhh, 256 + gidx);
          float rg = 1.f / (1.f + expf(-rp));
          float zg = 1.f / (1.f + expf(-zp));
          float ng = tanhf(inp + rg * hnp);
          float h = ldE<F32>(mem, (size_t)node * D_ + gidx);
          stE<F32>(out, (size_t)node * D_ + gidx, (1.f - zg) * ng + zg * h);
        }
      }
    }
    __syncthreads();
  }
}

__global__ __launch_bounds__(256, 3)
void k_gemm2(const void* mem, const void* lastup, const void* t, const void* feat,
             const int* src, const int* dst, const bf16* wpk,
             const void* bih, const void* bhh, const void* tw, const void* tb,
             const u32* __restrict__ flag, const u64* __restrict__ key,
             const int* __restrict__ list, const u32* __restrict__ cnt, int use_list,
             void* out, int N, int E) {
  if (use_list && (int)*cnt <= BM2 * (int)blockIdx.x) return;  // uniform, pre-barrier
  __shared__ __align__(16) char smem[41984];   // max(As2+Bs2=41984, Gs=17024)
  __shared__ int s_node[BM2], s_e[BM2], s_oth[BM2], s_act[BM2];
  __shared__ float s_dt[BM2], s_tw[128], s_tb[128];
  if (*flag)
    gemm2_body<true>(mem, lastup, t, feat, src, dst, wpk, bih, bhh, tw, tb,
                     key, list, cnt, use_list, out, N, E,
                     smem, s_node, s_e, s_oth, s_act, s_dt, s_tw, s_tb);
  else
    gemm2_body<false>(mem, lastup, t, feat, src, dst, wpk, bih, bhh, tw, tb,
                      key, list, cnt, use_list, out, N, E,
                      smem, s_node, s_e, s_oth, s_act, s_dt, s_tw, s_tb);
}

// ============================================================================
// FALLBACK: previous proven kernel (grid (mtiles,4)), used only if ws can't
// hold the packed weights. Only change: best[] -> low 32 bits of key[].
// ============================================================================
template<bool F32>
__device__ __forceinline__ void gemm_body(
    const void* mem, const void* lastup, const void* t, const void* feat,
    const int* __restrict__ src, const int* __restrict__ dst,
    const void* wih, const void* whh, const void* bih, const void* bhh,
    const void* tw, const void* tb,
    const u64* __restrict__ key, const int* __restrict__ list,
    const u32* __restrict__ cnt, int use_list,
    void* out, int N, int E,
    bf16 (*As)[72], bf16 (*Bs)[72], float (*Gs)[132],
    int* s_node, int* s_e, int* s_oth, int* s_act, float* s_dt) {
  const int tid = threadIdx.x;
  const int bx = blockIdx.x, by = blockIdx.y;

  if (tid < BM) {
    int r = tid;
    int row = BM * bx + r;
    int node = -1;
    if (use_list) { int c = (int)*cnt; if (row < c) node = list[row]; }
    else if (row < N) node = row;
    int act = 0, e = 0, oth = 0; float dtv = 0.f;
    if (node >= 0) {
      u32 b = (u32)key[node];
      if (b) {
        act = 1;
        int pos = (int)(b - 1u);
        if (pos < E) { e = pos; oth = dst[e]; } else { e = pos - E; oth = src[e]; }
        dtv = ldE<F32>(t, e) - ldE<F32>(lastup, node);
      }
    }
    if (node < 0) node = 0;
    s_node[r] = node; s_e[r] = e; s_oth[r] = oth; s_act[r] = act; s_dt[r] = dtv;
  }

  const int w = tid >> 6, l = tid & 63;
  const int mrow = l & 15, quad = l >> 4;
  f32x4 acc[4][2];
#pragma unroll
  for (int mi = 0; mi < 4; ++mi)
#pragma unroll
    for (int ni = 0; ni < 2; ++ni) acc[mi][ni] = (f32x4){0.f, 0.f, 0.f, 0.f};

#pragma unroll 1
  for (int kc = 0; kc < K_ / BK; ++kc) {
    __syncthreads();
#pragma unroll
    for (int it = 0; it < 2; ++it) {
      int task = tid + 256 * it;
      int r = task >> 3, s = task & 7;
      int k0 = kc * BK + s * 8;
      bf16* dstp = &As[r][s * 8];
      if (k0 < 128)       stage8<F32>(mem,  (size_t)s_node[r] * D_ + k0, dstp);
      else if (k0 < 256)  stage8<F32>(mem,  (size_t)s_oth[r] * D_ + (k0 - 128), dstp);
      else if (k0 < 384) {
        float dtv = s_dt[r];
        float f[8];
#pragma unroll
        for (int q = 0; q < 8; ++q) {
          int j = k0 - 256 + q;
          f[q] = cosf(fmaf(dtv, ldE<F32>(tw, j), ldE<F32>(tb, j)));
        }
        uint4 o; o.x = pk2(f[0], f[1]); o.y = pk2(f[2], f[3]);
        o.z = pk2(f[4], f[5]); o.w = pk2(f[6], f[7]);
        *(uint4*)dstp = o;
      }
      else if (k0 < 512)  stage8<F32>(feat, (size_t)s_e[r] * D_ + (k0 - 384), dstp);
      else                stage8<F32>(mem,  (size_t)s_node[r] * D_ + (k0 - 512), dstp);
    }
#pragma unroll
    for (int it = 0; it < 4; ++it) {
      int task = tid + 256 * it;
      int j = task >> 3, s = task & 7;
      int k0 = kc * BK + s * 8;
      int grp = j >> 5, gi = j & 31;
      int gidx = 32 * by + gi;
      bf16* dstp = &Bs[j][s * 8];
      if (k0 < 512) {
        if (grp == 3) { *(uint4*)dstp = (uint4){0, 0, 0, 0}; }
        else {
          int srow = (grp == 0) ? gidx : (grp == 1) ? 128 + gidx : 256 + gidx;
          stage8<F32>(wih, (size_t)srow * 512 + k0, dstp);
        }
      } else {
        if (grp == 2) { *(uint4*)dstp = (uint4){0, 0, 0, 0}; }
        else {
          int srow = (grp == 0) ? gidx : (grp == 1) ? 128 + gidx : 256 + gidx;
          stage8<F32>(whh, (size_t)srow * D_ + (k0 - 512), dstp);
        }
      }
    }
    __syncthreads();
#pragma unroll
    for (int ks = 0; ks < BK; ks += 32) {
      short8 a[4], b[2];
#pragma unroll
      for (int mi = 0; mi < 4; ++mi)
        a[mi] = *(const short8*)&As[16 * mi + mrow][ks + quad * 8];
#pragma unroll
      for (int ni = 0; ni < 2; ++ni)
        b[ni] = *(const short8*)&Bs[32 * w + 16 * ni + mrow][ks + quad * 8];
#pragma unroll
      for (int mi = 0; mi < 4; ++mi)
#pragma unroll
        for (int ni = 0; ni < 2; ++ni)
          acc[mi][ni] = __builtin_amdgcn_mfma_f32_16x16x32_bf16(a[mi], b[ni], acc[mi][ni], 0, 0, 0);
    }
  }

#pragma unroll
  for (int mi = 0; mi < 4; ++mi)
#pragma unroll
    for (int ni = 0; ni < 2; ++ni)
#pragma unroll
      for (int reg = 0; reg < 4; ++reg)
        Gs[16 * mi + quad * 4 + reg][32 * w + 16 * ni + mrow] = acc[mi][ni][reg];
  __syncthreads();

  {
    int r = tid >> 2;
    int giB = (tid & 3) * 8;
    if (s_act[r]) {
      int node = s_node[r];
#pragma unroll
      for (int q = 0; q < 8; ++q) {
        int gi = giB + q;
        int gidx = 32 * by + gi;
        float rp  = Gs[r][gi]       + ldE<F32>(bih, gidx)       + ldE<F32>(bhh, gidx);
        float zp  = Gs[r][32 + gi]  + ldE<F32>(bih, 128 + gidx) + ldE<F32>(bhh, 128 + gidx);
        float inp = Gs[r][64 + gi]  + ldE<F32>(bih, 256 + gidx);
        float hnp = Gs[r][96 + gi]  + ldE<F32>(bhh, 256 + gidx);
        float rg = 1.f / (1.f + expf(-rp));
        float zg = 1.f / (1.f + expf(-zp));
        float ng = tanhf(inp + rg * hnp);
        float h = ldE<F32>(mem, (size_t)node * D_ + gidx);
        stE<F32>(out, (size_t)node * D_ + gidx, (1.f - zg) * ng + zg * h);
      }
    }
  }
}

__global__ __launch_bounds__(256)
void k_gemm_fb(const void* mem, const void* lastup, const void* t, const void* feat,
               const int* src, const int* dst,
               const void* wih, const void* whh, const void* bih, const void* bhh,
               const void* tw, const void* tb,
               const u32* __restrict__ flag, const u64* __restrict__ key,
               const int* __restrict__ list, const u32* __restrict__ cnt, int use_list,
               void* out, int N, int E) {
  if (use_list && (int)*cnt <= BM * (int)blockIdx.x) return;

  __shared__ __align__(16) bf16 As[BM][72];
  __shared__ __align__(16) bf16 Bs[BN][72];
  __shared__ __align__(16) float Gs[BM][132];
  __shared__ int s_node[BM], s_e[BM], s_oth[BM], s_act[BM];
  __shared__ float s_dt[BM];

  if (*flag)
    gemm_body<true>(mem, lastup, t, feat, src, dst, wih, whh, bih, bhh, tw, tb,
                    key, list, cnt, use_list, out, N, E,
                    As, Bs, Gs, s_node, s_e, s_oth, s_act, s_dt);
  else
    gemm_body<false>(mem, lastup, t, feat, src, dst, wih, whh, bih, bhh, tw, tb,
                     key, list, cnt, use_list, out, N, E,
                     As, Bs, Gs, s_node, s_e, s_oth, s_act, s_dt);
}

extern "C" void kernel_launch(void* const* d_in, const int* in_sizes, int n_in,
                              void* d_out, int out_size, void* d_ws, size_t ws_size,
                              hipStream_t stream) {
  const void* mem    = d_in[0];
  const void* lastup = d_in[1];
  const void* t      = d_in[2];
  const void* feat   = d_in[3];
  const void* tw     = d_in[4];
  const void* tb     = d_in[5];
  const void* wih    = d_in[6];
  const void* whh    = d_in[7];
  const void* bih    = d_in[8];
  const void* bhh    = d_in[9];
  const int*  src    = (const int*)d_in[10];
  const int*  dst    = (const int*)d_in[11];

  int N = in_sizes[0] / D_;
  int E = in_sizes[2];

  // ws layout: flag(16) + cnt(16) + key[N](8N) + list[N](4N, optional)
  //            + wpk(512*640 bf16 = 655360B, optional -> fallback kernel)
  char* ws = (char*)d_ws;
  size_t off = 0;
  u32* flag = (u32*)(ws + off); off += 16;
  u32* cnt  = (u32*)(ws + off); off += 16;
  u64* key  = (u64*)(ws + off); off += (size_t)N * 8;
  int* list = (int*)(ws + off); off += (size_t)N * 4;
  int use_list = (ws_size >= off) ? 1 : 0;
  bf16* wpk = (bf16*)(ws + off); off += (size_t)512 * 640 * 2;
  int use_wpk = (ws_size >= off) ? 1 : 0;

  const int thr = 256;
  int nb  = (N + thr - 1) / thr;
  int eb  = (2 * E + thr - 1) / thr;

  k_prep<<<dim3(nb), dim3(thr), 0, stream>>>(key, cnt, N, (const u32*)mem, (const u32*)t, flag);
  k_scat<<<dim3(eb), dim3(thr), 0, stream>>>(src, dst, t, flag, key, E);
  if (use_wpk)
    k_pack<<<dim3(160), dim3(thr), 0, stream>>>(wih, whh, flag, wpk);
  k_compact<<<dim3(nb), dim3(thr), 0, stream>>>(mem, lastup, t, flag, key,
                                                list, cnt, use_list, d_out, N, E);
  if (use_wpk) {
    int mt = (N + BM2 - 1) / BM2;
    k_gemm2<<<dim3(mt), dim3(thr), 0, stream>>>(
        mem, lastup, t, feat, src, dst, wpk, bih, bhh, tw, tb,
        flag, key, list, cnt, use_list, d_out, N, E);
  } else {
    int mt = (N + BM - 1) / BM;
    k_gemm_fb<<<dim3(mt, 4), dim3(thr), 0, stream>>>(
        mem, lastup, t, feat, src, dst, wih, whh, bih, bhh, tw, tb,
        flag, key, list, cnt, use_list, d_out, N, E);
  }
}